// Round 5
// baseline (234.591 us; speedup 1.0000x reference)
//
#include <hip/hip_runtime.h>

// EMA energy normalizer: mag [B,F,T] fp32 -> (mag_norm [B,F,T], mag_mean [B,1,T])
//
// R4 accounting: harness fills ~140us fixed; controllable slice ~65us vs ~40us floor.
// This round: (a) kill the part[] round-trip via atomic funnel into framesum[B][T],
// (b) fuse scan+normalize (every block redundantly scans its batch's 12KB framesum
// row in LDS — removes the 32-block latency-bound K2 straggler and one graph node),
// (c) recip comes from LDS/registers in the normalize loop.
//
// K0: zero framesum (384 KB)                                   ~1us
// K1: row-streaming F-sums, 1024 blocks, relaxed atomicAdd out ~17us (FETCH 99MB)
// K2: fused scan+normalize, 1024 blocks                        ~30us (WRITE 99MB)

#define B_  32
#define F_  257
#define T_  3000
#define T4  750       // T/4 float4s per row
#define NCH 32        // f-chunks; grids = B*NCH = 1024 blocks
#define MOM 0.99f
#define OMM 0.01f
#define EPS_ 1e-8f

// ---------------------------------------------------------------------------
// K0: zero the framesum accumulator (d_ws is poisoned 0xAA before every call).
// ---------------------------------------------------------------------------
__global__ __launch_bounds__(256) void k0_zero(float4* __restrict__ fs4) {
    int i = blockIdx.x * 256 + threadIdx.x;     // B*T/4 = 24000 float4s
    if (i < B_ * T4) fs4[i] = make_float4(0.f, 0.f, 0.f, 0.f);
}

// ---------------------------------------------------------------------------
// K1: block = (b, c). Streams rows f in [f0,f1) (8-9 rows, 12 KB each) fully
// contiguously; 3 fixed t4-slots in registers; 12 relaxed device-scope
// atomicAdds into framesum[b][t] at the end (per-address fan-in = NCH = 32).
// ---------------------------------------------------------------------------
__global__ __launch_bounds__(256) void k1_rowsum(const float* __restrict__ mag,
                                                 float* __restrict__ framesum) {
    const int blk = blockIdx.x;       // b*NCH + c
    const int b   = blk >> 5;
    const int c   = blk & (NCH - 1);
    const int f0  = (c * F_) >> 5;
    const int f1  = ((c + 1) * F_) >> 5;
    const int tid = threadIdx.x;
    const float4* magv = reinterpret_cast<const float4*>(mag);

    float4 a0 = make_float4(0.f, 0.f, 0.f, 0.f);
    float4 a1 = a0, a2 = a0;
    const bool has2 = tid < (T4 - 512);   // slots: tid, tid+256, tid+512(<750)

    int base = (b * F_ + f0) * T4;
    for (int f = f0; f < f1; ++f, base += T4) {
        float4 v0 = magv[base + tid];
        float4 v1 = magv[base + tid + 256];
        a0.x += v0.x; a0.y += v0.y; a0.z += v0.z; a0.w += v0.w;
        a1.x += v1.x; a1.y += v1.y; a1.z += v1.z; a1.w += v1.w;
        if (has2) {
            float4 v2 = magv[base + tid + 512];
            a2.x += v2.x; a2.y += v2.y; a2.z += v2.z; a2.w += v2.w;
        }
    }
    float* fs = framesum + b * T_;
    int t = tid * 4;
    __hip_atomic_fetch_add(fs + t,     a0.x, __ATOMIC_RELAXED, __HIP_MEMORY_SCOPE_AGENT);
    __hip_atomic_fetch_add(fs + t + 1, a0.y, __ATOMIC_RELAXED, __HIP_MEMORY_SCOPE_AGENT);
    __hip_atomic_fetch_add(fs + t + 2, a0.z, __ATOMIC_RELAXED, __HIP_MEMORY_SCOPE_AGENT);
    __hip_atomic_fetch_add(fs + t + 3, a0.w, __ATOMIC_RELAXED, __HIP_MEMORY_SCOPE_AGENT);
    t += 1024;
    __hip_atomic_fetch_add(fs + t,     a1.x, __ATOMIC_RELAXED, __HIP_MEMORY_SCOPE_AGENT);
    __hip_atomic_fetch_add(fs + t + 1, a1.y, __ATOMIC_RELAXED, __HIP_MEMORY_SCOPE_AGENT);
    __hip_atomic_fetch_add(fs + t + 2, a1.z, __ATOMIC_RELAXED, __HIP_MEMORY_SCOPE_AGENT);
    __hip_atomic_fetch_add(fs + t + 3, a1.w, __ATOMIC_RELAXED, __HIP_MEMORY_SCOPE_AGENT);
    if (has2) {
        t += 1024;
        __hip_atomic_fetch_add(fs + t,     a2.x, __ATOMIC_RELAXED, __HIP_MEMORY_SCOPE_AGENT);
        __hip_atomic_fetch_add(fs + t + 1, a2.y, __ATOMIC_RELAXED, __HIP_MEMORY_SCOPE_AGENT);
        __hip_atomic_fetch_add(fs + t + 2, a2.z, __ATOMIC_RELAXED, __HIP_MEMORY_SCOPE_AGENT);
        __hip_atomic_fetch_add(fs + t + 3, a2.w, __ATOMIC_RELAXED, __HIP_MEMORY_SCOPE_AGENT);
    }
}

// ---------------------------------------------------------------------------
// K2: fused scan + normalize. block = (b, c), 1024 blocks. Each block
// redundantly: loads framesum row (12 KB, L2), scans (Hillis-Steele over
// affine maps), stores recip in LDS; c==0 blocks write mag_mean; then
// normalizes rows [f0,f1) with register-held recips.
// ---------------------------------------------------------------------------
__global__ __launch_bounds__(256) void k2_scan_norm(const float* __restrict__ framesum,
                                                    const float* __restrict__ bias,
                                                    const float* __restrict__ rmean,
                                                    const float* __restrict__ mag,
                                                    float* __restrict__ out,
                                                    float* __restrict__ mag_mean) {
    __shared__ float4 xs4[T4];            // 12 KB
    float* xs = reinterpret_cast<float*>(xs4);
    __shared__ float sA[256];
    __shared__ float sB[256];

    const int blk = blockIdx.x;           // b*NCH + c
    const int b   = blk >> 5;
    const int c   = blk & (NCH - 1);
    const int f0  = (c * F_) >> 5;
    const int f1  = ((c + 1) * F_) >> 5;
    const int tid = threadIdx.x;

    // frame means into LDS
    {
        const float4* fsv = reinterpret_cast<const float4*>(framesum) + b * T4;
        const float inv_f = 1.0f / F_;
        for (int i = tid; i < T4; i += 256) {
            float4 v = fsv[i];
            v.x *= inv_f; v.y *= inv_f; v.z *= inv_f; v.w *= inv_f;
            xs4[i] = v;
        }
    }
    __syncthreads();

    // local chunk scan: 250 active threads x 12 steps
    const int CH = 12;
    const int t0 = tid * CH;
    float A = 1.f, Bv = 0.f;
    if (t0 < T_) {
        #pragma unroll
        for (int j = 0; j < CH; ++j) {
            Bv = MOM * Bv + OMM * xs[t0 + j];
            A *= MOM;
        }
    }
    sA[tid] = A; sB[tid] = Bv;
    __syncthreads();

    // Hillis-Steele over affine maps: (Ap,Bp)∘(Ac,Bc) = (Ap*Ac, Bp*Ac+Bc)
    for (int off = 1; off < 256; off <<= 1) {
        float cA = sA[tid], cB = sB[tid];
        float pA = 1.f, pB = 0.f;
        if (tid >= off) { pA = sA[tid - off]; pB = sB[tid - off]; }
        __syncthreads();
        if (tid >= off) { sA[tid] = pA * cA; sB[tid] = pB * cA + cB; }
        __syncthreads();
    }

    float pA = 1.f, pB = 0.f;
    if (tid > 0) { pA = sA[tid - 1]; pB = sB[tid - 1]; }
    __syncthreads();

    const float bias0 = bias[0];
    if (t0 < T_) {
        float m = pA * rmean[0] + pB;        // m_{t0-1}
        #pragma unroll
        for (int j = 0; j < CH; ++j) {
            m = MOM * m + OMM * xs[t0 + j];
            xs[t0 + j] = m + bias0;          // mean + bias
        }
    }
    __syncthreads();

    // c==0 blocks emit mag_mean; then everyone flips xs to reciprocals
    if (c == 0) {
        for (int i = tid; i < T4; i += 256)
            reinterpret_cast<float4*>(mag_mean + b * T_)[i] = xs4[i];
    }
    for (int i = tid; i < T4; i += 256) {
        float4 v = xs4[i];
        v.x = 1.0f / (v.x + EPS_); v.y = 1.0f / (v.y + EPS_);
        v.z = 1.0f / (v.z + EPS_); v.w = 1.0f / (v.w + EPS_);
        xs4[i] = v;
    }
    __syncthreads();

    // normalize rows [f0,f1): recips in registers, 3 float4 slots/thread
    const float4* magv = reinterpret_cast<const float4*>(mag);
    float4* ov = reinterpret_cast<float4*>(out);
    const bool has2 = tid < (T4 - 512);
    const float4 r0 = xs4[tid];
    const float4 r1 = xs4[tid + 256];
    const float4 r2 = has2 ? xs4[tid + 512] : r0;
    int base = (b * F_ + f0) * T4;
    for (int f = f0; f < f1; ++f, base += T4) {
        float4 v0 = magv[base + tid];
        float4 v1 = magv[base + tid + 256];
        float4 o;
        o.x = v0.x * r0.x; o.y = v0.y * r0.y; o.z = v0.z * r0.z; o.w = v0.w * r0.w;
        ov[base + tid] = o;
        o.x = v1.x * r1.x; o.y = v1.y * r1.y; o.z = v1.z * r1.z; o.w = v1.w * r1.w;
        ov[base + tid + 256] = o;
        if (has2) {
            float4 v2 = magv[base + tid + 512];
            o.x = v2.x * r2.x; o.y = v2.y * r2.y; o.z = v2.z * r2.z; o.w = v2.w * r2.w;
            ov[base + tid + 512] = o;
        }
    }
}

extern "C" void kernel_launch(void* const* d_in, const int* in_sizes, int n_in,
                              void* d_out, int out_size, void* d_ws, size_t ws_size,
                              hipStream_t stream) {
    const float* mag   = (const float*)d_in[0];
    const float* bias  = (const float*)d_in[1];
    const float* rmean = (const float*)d_in[2];
    float* out      = (float*)d_out;
    float* mag_mean = out + (size_t)B_ * F_ * T_;     // second tuple output
    float* framesum = (float*)d_ws;                   // B*T floats = 384 KB

    k0_zero<<<(B_ * T4 + 255) / 256, 256, 0, stream>>>((float4*)framesum);
    k1_rowsum<<<B_ * NCH, 256, 0, stream>>>(mag, framesum);
    k2_scan_norm<<<B_ * NCH, 256, 0, stream>>>(framesum, bias, rmean, mag, out, mag_mean);
}

// Round 6
// 196.129 us; speedup vs baseline: 1.1961x; 1.1961x over previous
//
#include <hip/hip_runtime.h>

// EMA energy normalizer: mag [B,F,T] fp32 -> (mag_norm [B,F,T], mag_mean [B,1,T])
//
// R5 lesson: bulk device-scope fp32 atomics ~60M/s (16ns each) — the atomic
// funnel cost +50us and 48MB of write amplification. This round: t-segment
// reduction writes framesum[B][T] directly (no atomics, no part[] round-trip).
//
// K1': 800 blocks = (b, 25 t-segments). Block reduces all 257 f's for its
//      120-t segment: 8 f-groups x 30 float4-slots, LDS reduce, one 480B write.
// K2': fused scan+normalize (R5's K2, passed): redundant per-block 12KB scan
//      (L2 broadcast), Hillis-Steele over affine maps, register-held recips.

#define B_   32
#define F_   257
#define T_   3000
#define T4   750      // T/4 float4s per row
#define NSEG 25       // t-segments per batch; K1 grid = B*NSEG = 800
#define SEG4 30       // float4s per segment (120 floats)
#define NCH  32       // f-chunks for K2; grid = B*NCH = 1024
#define MOM 0.99f
#define OMM 0.01f
#define EPS_ 1e-8f

// ---------------------------------------------------------------------------
// K1': block (b, s). Thread (g, slot), g<8, slot<30: acc over f = g, g+8, ...
// (<=33 contiguous 16B loads at 96KB stride). LDS reduce over g, single
// coalesced 480B framesum write. No atomics.
// ---------------------------------------------------------------------------
__global__ __launch_bounds__(256) void k1_seg(const float* __restrict__ mag,
                                              float* __restrict__ framesum) {
    __shared__ float4 red[8][SEG4];       // 3.75 KB
    const int blk = blockIdx.x;           // b*NSEG + s
    const int b   = blk / NSEG;
    const int s   = blk % NSEG;
    const int tid = threadIdx.x;
    const int g    = tid / SEG4;          // f-group; g>=8 -> idle
    const int slot = tid % SEG4;

    if (g < 8) {
        const float4* magv = reinterpret_cast<const float4*>(mag);
        const int col = s * SEG4 + slot;  // float4 column in [0, T4)
        float4 a = make_float4(0.f, 0.f, 0.f, 0.f);
        int idx = (b * F_ + g) * T4 + col;
        const int step = 8 * T4;
        #pragma unroll 4
        for (int f = g; f < F_; f += 8, idx += step) {
            float4 v = magv[idx];
            a.x += v.x; a.y += v.y; a.z += v.z; a.w += v.w;
        }
        red[g][slot] = a;
    }
    __syncthreads();

    if (tid < SEG4) {
        float4 a = red[0][tid];
        #pragma unroll
        for (int gg = 1; gg < 8; ++gg) {
            float4 v = red[gg][tid];
            a.x += v.x; a.y += v.y; a.z += v.z; a.w += v.w;
        }
        reinterpret_cast<float4*>(framesum)[b * T4 + s * SEG4 + tid] = a;
    }
}

// ---------------------------------------------------------------------------
// K2': fused scan + normalize. block = (b, c), 1024 blocks. Each block:
// loads framesum row (12 KB, L2 broadcast), scans (Hillis-Steele over affine
// maps (A,B): m' = A*m + B), c==0 writes mag_mean, flips to recip in LDS,
// normalizes rows [f0,f1) with register-held recips.
// ---------------------------------------------------------------------------
__global__ __launch_bounds__(256) void k2_scan_norm(const float* __restrict__ framesum,
                                                    const float* __restrict__ bias,
                                                    const float* __restrict__ rmean,
                                                    const float* __restrict__ mag,
                                                    float* __restrict__ out,
                                                    float* __restrict__ mag_mean) {
    __shared__ float4 xs4[T4];            // 12 KB
    float* xs = reinterpret_cast<float*>(xs4);
    __shared__ float sA[256];
    __shared__ float sB[256];

    const int blk = blockIdx.x;           // b*NCH + c
    const int b   = blk >> 5;
    const int c   = blk & (NCH - 1);
    const int f0  = (c * F_) >> 5;
    const int f1  = ((c + 1) * F_) >> 5;
    const int tid = threadIdx.x;

    // frame means into LDS
    {
        const float4* fsv = reinterpret_cast<const float4*>(framesum) + b * T4;
        const float inv_f = 1.0f / F_;
        for (int i = tid; i < T4; i += 256) {
            float4 v = fsv[i];
            v.x *= inv_f; v.y *= inv_f; v.z *= inv_f; v.w *= inv_f;
            xs4[i] = v;
        }
    }
    __syncthreads();

    // local chunk scan: 250 active threads x 12 steps
    const int CH = 12;
    const int t0 = tid * CH;
    float A = 1.f, Bv = 0.f;
    if (t0 < T_) {
        #pragma unroll
        for (int j = 0; j < CH; ++j) {
            Bv = MOM * Bv + OMM * xs[t0 + j];
            A *= MOM;
        }
    }
    sA[tid] = A; sB[tid] = Bv;
    __syncthreads();

    // Hillis-Steele over affine maps: (Ap,Bp)∘(Ac,Bc) = (Ap*Ac, Bp*Ac+Bc)
    for (int off = 1; off < 256; off <<= 1) {
        float cA = sA[tid], cB = sB[tid];
        float pA = 1.f, pB = 0.f;
        if (tid >= off) { pA = sA[tid - off]; pB = sB[tid - off]; }
        __syncthreads();
        if (tid >= off) { sA[tid] = pA * cA; sB[tid] = pB * cA + cB; }
        __syncthreads();
    }

    float pA = 1.f, pB = 0.f;
    if (tid > 0) { pA = sA[tid - 1]; pB = sB[tid - 1]; }
    __syncthreads();

    const float bias0 = bias[0];
    if (t0 < T_) {
        float m = pA * rmean[0] + pB;        // m_{t0-1}
        #pragma unroll
        for (int j = 0; j < CH; ++j) {
            m = MOM * m + OMM * xs[t0 + j];
            xs[t0 + j] = m + bias0;          // mean + bias
        }
    }
    __syncthreads();

    // c==0 blocks emit mag_mean; then everyone flips xs to reciprocals
    if (c == 0) {
        for (int i = tid; i < T4; i += 256)
            reinterpret_cast<float4*>(mag_mean + b * T_)[i] = xs4[i];
    }
    for (int i = tid; i < T4; i += 256) {
        float4 v = xs4[i];
        v.x = 1.0f / (v.x + EPS_); v.y = 1.0f / (v.y + EPS_);
        v.z = 1.0f / (v.z + EPS_); v.w = 1.0f / (v.w + EPS_);
        xs4[i] = v;
    }
    __syncthreads();

    // normalize rows [f0,f1): recips in registers, 3 float4 slots/thread
    const float4* magv = reinterpret_cast<const float4*>(mag);
    float4* ov = reinterpret_cast<float4*>(out);
    const bool has2 = tid < (T4 - 512);
    const float4 r0 = xs4[tid];
    const float4 r1 = xs4[tid + 256];
    const float4 r2 = has2 ? xs4[tid + 512] : r0;
    int base = (b * F_ + f0) * T4;
    for (int f = f0; f < f1; ++f, base += T4) {
        float4 v0 = magv[base + tid];
        float4 v1 = magv[base + tid + 256];
        float4 o;
        o.x = v0.x * r0.x; o.y = v0.y * r0.y; o.z = v0.z * r0.z; o.w = v0.w * r0.w;
        ov[base + tid] = o;
        o.x = v1.x * r1.x; o.y = v1.y * r1.y; o.z = v1.z * r1.z; o.w = v1.w * r1.w;
        ov[base + tid + 256] = o;
        if (has2) {
            float4 v2 = magv[base + tid + 512];
            o.x = v2.x * r2.x; o.y = v2.y * r2.y; o.z = v2.z * r2.z; o.w = v2.w * r2.w;
            ov[base + tid + 512] = o;
        }
    }
}

extern "C" void kernel_launch(void* const* d_in, const int* in_sizes, int n_in,
                              void* d_out, int out_size, void* d_ws, size_t ws_size,
                              hipStream_t stream) {
    const float* mag   = (const float*)d_in[0];
    const float* bias  = (const float*)d_in[1];
    const float* rmean = (const float*)d_in[2];
    float* out      = (float*)d_out;
    float* mag_mean = out + (size_t)B_ * F_ * T_;     // second tuple output
    float* framesum = (float*)d_ws;                   // B*T floats = 384 KB

    k1_seg<<<B_ * NSEG, 256, 0, stream>>>(mag, framesum);
    k2_scan_norm<<<B_ * NCH, 256, 0, stream>>>(framesum, bias, rmean, mag, out, mag_mean);
}